// Round 1
// baseline (383.298 us; speedup 1.0000x reference)
//
#include <hip/hip_runtime.h>

typedef _Float16 half8 __attribute__((ext_vector_type(8)));
typedef float floatx4 __attribute__((ext_vector_type(4)));

#define B_DIM 8
#define C_DIM 64
#define T_DIM 128
#define N_DIM 207
#define O_DIM 64
#define CSTR  (T_DIM * N_DIM)

// ---------------------------------------------------------------------------
// Kernel 0: pack Wq|Wk|Wv (fp32 [64 o][64 c]) -> fp16 in d_ws. [arr][o][c].
// ---------------------------------------------------------------------------
__global__ void pack_w(const float* __restrict__ Wq,
                       const float* __restrict__ Wk,
                       const float* __restrict__ Wv,
                       _Float16* __restrict__ ws)
{
    int i = threadIdx.x + blockIdx.x * blockDim.x;
    const int per = O_DIM * C_DIM;          // 4096
    for (int m = i; m < 3 * per; m += blockDim.x * gridDim.x) {
        int arr = m / per, rem = m % per;
        const float* W = (arr == 0) ? Wq : (arr == 1) ? Wk : Wv;
        ws[m] = (_Float16)W[rem];
    }
}

// ---------------------------------------------------------------------------
// Main: t-marching MFMA kernel, 32-wide n-tiles.
// Block 512 thr = 8 waves. Waves 0-3: n-sub 0 (o-slices 0..3), waves 4-7:
// n-sub 1. Staging lanes read 32 consecutive n = full 128B lines. 2-deep
// register prefetch (pfA/pfB, statically indexed). Q loads/MFMA skipped on
// the 6 halo steps. XCD-contiguous tile mapping (XCD x owns batch x).
// ---------------------------------------------------------------------------

// load one t-row of (q?,k,v) into pf[3][4]; 4 channels per thread per array
#define LOADROW(pf, tg1, withQ)                                              \
    {                                                                        \
        const int tcl_ = min(max((tg1), 0), T_DIM - 1);                      \
        if (withQ) {                                                         \
            const float* p_ = qb + (size_t)tcl_ * N_DIM;                     \
            pf[0][0] = p_[(2 * cp2     ) * CSTR];                            \
            pf[0][1] = p_[(2 * cp2 +  1) * CSTR];                            \
            pf[0][2] = p_[(2 * cp2 + 32) * CSTR];                            \
            pf[0][3] = p_[(2 * cp2 + 33) * CSTR];                            \
        }                                                                    \
        {                                                                    \
            const float* p_ = kb + (size_t)tcl_ * N_DIM;                     \
            pf[1][0] = p_[(2 * cp2     ) * CSTR];                            \
            pf[1][1] = p_[(2 * cp2 +  1) * CSTR];                            \
            pf[1][2] = p_[(2 * cp2 + 32) * CSTR];                            \
            pf[1][3] = p_[(2 * cp2 + 33) * CSTR];                            \
        }                                                                    \
        {                                                                    \
            const float* p_ = vb + (size_t)tcl_ * N_DIM;                     \
            pf[2][0] = p_[(2 * cp2     ) * CSTR];                            \
            pf[2][1] = p_[(2 * cp2 +  1) * CSTR];                            \
            pf[2][2] = p_[(2 * cp2 + 32) * CSTR];                            \
            pf[2][3] = p_[(2 * cp2 + 33) * CSTR];                            \
        }                                                                    \
    }

// one t-step: scatter row r (held in pf) to LDS buf, prefetch row r+2 into
// pf, barrier, MFMA projections, window shift/insert, emit row r-6.
#define STEP(r, BUF, pf)                                                     \
    {                                                                        \
        const int  r_  = (r);                                                \
        const bool qs_ = (r_ >= 3) && (r_ <= 18);                            \
        {                                                                    \
            auto pk0 = __builtin_amdgcn_cvt_pkrtz(pf[1][0], pf[1][1]);       \
            auto pk1 = __builtin_amdgcn_cvt_pkrtz(pf[1][2], pf[1][3]);       \
            auto pv0 = __builtin_amdgcn_cvt_pkrtz(pf[2][0], pf[2][1]);       \
            auto pv1 = __builtin_amdgcn_cvt_pkrtz(pf[2][2], pf[2][3]);       \
            xw[(BUF) * 3072 + 2 * 512 + sbase] = __builtin_bit_cast(unsigned int, pk0); \
            xw[(BUF) * 3072 + 3 * 512 + sbase] = __builtin_bit_cast(unsigned int, pk1); \
            xw[(BUF) * 3072 + 4 * 512 + sbase] = __builtin_bit_cast(unsigned int, pv0); \
            xw[(BUF) * 3072 + 5 * 512 + sbase] = __builtin_bit_cast(unsigned int, pv1); \
            if (qs_) {                                                       \
                auto pq0 = __builtin_amdgcn_cvt_pkrtz(pf[0][0], pf[0][1]);   \
                auto pq1 = __builtin_amdgcn_cvt_pkrtz(pf[0][2], pf[0][3]);   \
                xw[(BUF) * 3072 + 0 * 512 + sbase] = __builtin_bit_cast(unsigned int, pq0); \
                xw[(BUF) * 3072 + 1 * 512 + sbase] = __builtin_bit_cast(unsigned int, pq1); \
            }                                                                \
        }                                                                    \
        if (r_ <= 19) {                                                      \
            const bool wq_ = (r_ >= 1) && (r_ <= 16);                        \
            LOADROW(pf, t0 - 1 + r_, wq_)                                    \
        }                                                                    \
        __syncthreads();                                                     \
        floatx4 aq = {0.f, 0.f, 0.f, 0.f};                                   \
        floatx4 ak = {0.f, 0.f, 0.f, 0.f};                                   \
        floatx4 av = {0.f, 0.f, 0.f, 0.f};                                   \
        ak = __builtin_amdgcn_mfma_f32_16x16x32_f16(af[1][0], xsf[BUF][ 4 + hn][lane], ak, 0, 0, 0); \
        ak = __builtin_amdgcn_mfma_f32_16x16x32_f16(af[1][1], xsf[BUF][ 6 + hn][lane], ak, 0, 0, 0); \
        av = __builtin_amdgcn_mfma_f32_16x16x32_f16(af[2][0], xsf[BUF][ 8 + hn][lane], av, 0, 0, 0); \
        av = __builtin_amdgcn_mfma_f32_16x16x32_f16(af[2][1], xsf[BUF][10 + hn][lane], av, 0, 0, 0); \
        if (qs_) {                                                           \
            aq = __builtin_amdgcn_mfma_f32_16x16x32_f16(af[0][0], xsf[BUF][0 + hn][lane], aq, 0, 0, 0); \
            aq = __builtin_amdgcn_mfma_f32_16x16x32_f16(af[0][1], xsf[BUF][2 + hn][lane], aq, 0, 0, 0); \
        }                                                                    \
        const int  tg_   = t0 - 3 + r_;                                      \
        const bool rowv_ = (tg_ >= 0) && (tg_ < T_DIM);                      \
        _Pragma("unroll")                                                    \
        for (int j = 0; j < 4; ++j) {                                        \
            _Pragma("unroll")                                                \
            for (int i = 0; i < 6; ++i) { Kw[j][i] = Kw[j][i + 1]; Vw[j][i] = Vw[j][i + 1]; } \
            _Pragma("unroll")                                                \
            for (int i = 0; i < 3; ++i) Qd4[j][i] = Qd4[j][i + 1];           \
            Kw[j][6]  = rowv_ ? (ak[j] + bk_r[j]) : 0.f;                     \
            Vw[j][6]  = rowv_ ? (av[j] + bv_r[j]) : 0.f;                     \
            Qd4[j][3] = aq[j] + bq_r[j];                                     \
        }                                                                    \
        if (r_ >= 6) {                                                       \
            const int to_ = t0 + r_ - 6;                                     \
            const int n_g = n0 + hn * 16 + nq;                               \
            if (n_g < N_DIM) {                                               \
                _Pragma("unroll")                                            \
                for (int j = 0; j < 4; ++j) {                                \
                    const float qv = Qd4[j][0] * 1.44269504f;                \
                    float s[7];                                              \
                    _Pragma("unroll")                                        \
                    for (int i = 0; i < 7; ++i) s[i] = qv * Kw[j][i];        \
                    float mx = s[0];                                         \
                    _Pragma("unroll")                                        \
                    for (int i = 1; i < 7; ++i) mx = fmaxf(mx, s[i]);        \
                    float den = 0.f, num = 0.f;                              \
                    _Pragma("unroll")                                        \
                    for (int i = 0; i < 7; ++i) {                            \
                        float e = exp2f(s[i] - mx);                          \
                        den += e;                                            \
                        num = fmaf(e, Vw[j][i], num);                        \
                    }                                                        \
                    out[((size_t)(b * O_DIM + o0 + qd * 4 + j) * T_DIM + to_) * N_DIM + n_g] \
                        = num * __builtin_amdgcn_rcpf(den);                  \
                }                                                            \
            }                                                                \
        }                                                                    \
    }

__global__ __launch_bounds__(512, 4)
void attn_mfma(const float* __restrict__ q,
               const float* __restrict__ k,
               const float* __restrict__ v,
               const float* __restrict__ bq,
               const float* __restrict__ bk,
               const float* __restrict__ bv,
               const _Float16* __restrict__ wpk,
               float* __restrict__ out)
{
    // [buf][(arr*2+kk)*2 + h][lane] fragment-ordered X staging: 24576 B
    __shared__ half8 xsf[2][12][64];

    const int tid  = threadIdx.x;
    const int lane = tid & 63;
    const int wv   = tid >> 6;        // 0..7
    const int hn   = wv >> 2;         // n-sub this wave computes
    const int nq   = lane & 15;       // D col (n), A row (m)
    const int qd   = lane >> 4;       // quad

    // XCD-contiguous tile mapping: hw block i -> XCD i%8; give XCD x the
    // contiguous tile range [x*56, (x+1)*56) = all tiles of batch x.
    const int bid = blockIdx.x + 7 * (blockIdx.y + 8 * (int)blockIdx.z);
    const int swz = (bid & 7) * 56 + (bid >> 3);
    const int nb  = swz % 7;          // 0..6  (32 n each)
    const int tc  = (swz / 7) & 7;    // 0..7  (16 t each)
    const int b   = swz / 56;         // 0..7

    const int t0 = tc * 16;
    const int o0 = (wv & 3) * 16;
    const int n0 = nb * 32;

    // ---- staging mapping: thread -> (n = n0+sn, c-pairs 2cp2 & 2cp2+32) ----
    const int sn    = tid & 31;       // 32 consecutive n = 128B lines
    const int cp2   = tid >> 5;       // 0..15
    const int wq    = cp2 >> 2;       // frag quad of staged elements
    const int jp    = cp2 & 3;        // dword-pair index within frag
    const int sbase = ((sn >> 4) * 64 + wq * 16 + (sn & 15)) * 4 + jp;

    const int n_sc = min(n0 + sn, N_DIM - 1);
    const float* qb = q + (size_t)b * C_DIM * CSTR + n_sc;
    const float* kb = k + (size_t)b * C_DIM * CSTR + n_sc;
    const float* vb = v + (size_t)b * C_DIM * CSTR + n_sc;

    // ---- loop-invariant A-fragments: W[o0+m][k], m=nq, k=qd*8+j+kk*32 ----
    half8 af[3][2];
    #pragma unroll
    for (int arr = 0; arr < 3; ++arr)
        #pragma unroll
        for (int kk = 0; kk < 2; ++kk)
            af[arr][kk] = *(const half8*)(wpk + ((size_t)(arr * 64 + o0 + nq) * 64
                                                 + qd * 8 + kk * 32));

    // ---- bias per lane-reg: D row o_l = qd*4+reg ----
    float bq_r[4], bk_r[4], bv_r[4];
    #pragma unroll
    for (int j = 0; j < 4; ++j) {
        const int og = o0 + qd * 4 + j;
        bq_r[j] = bq[og]; bk_r[j] = bk[og]; bv_r[j] = bv[og];
    }

    // ---- rolling windows ----
    float Kw[4][7], Vw[4][7], Qd4[4][4];
    #pragma unroll
    for (int j = 0; j < 4; ++j) {
        #pragma unroll
        for (int i = 0; i < 7; ++i) { Kw[j][i] = 0.f; Vw[j][i] = 0.f; }
        #pragma unroll
        for (int i = 0; i < 4; ++i) Qd4[j][i] = 0.f;
    }

    unsigned int* xw = (unsigned int*)&xsf[0][0][0];

    // ---- 2-deep prefetch: pfA holds row for even step, pfB for odd ----
    float pfA[3][4], pfB[3][4];
    #pragma unroll
    for (int a2 = 0; a2 < 3; ++a2)
        #pragma unroll
        for (int j = 0; j < 4; ++j) { pfA[a2][j] = 0.f; pfB[a2][j] = 0.f; }

    LOADROW(pfA, t0 - 3, false)       // row for step 0 (no Q on halo)
    LOADROW(pfB, t0 - 2, false)       // row for step 1

    for (int r2 = 0; r2 < 11; ++r2) {
        STEP(2 * r2,     0, pfA);     // buf/pf statically indexed (rule #20)
        STEP(2 * r2 + 1, 1, pfB);
    }
}

extern "C" void kernel_launch(void* const* d_in, const int* in_sizes, int n_in,
                              void* d_out, int out_size, void* d_ws, size_t ws_size,
                              hipStream_t stream)
{
    const float* q  = (const float*)d_in[0];
    const float* k  = (const float*)d_in[1];
    const float* v  = (const float*)d_in[2];
    const float* Wq = (const float*)d_in[3];
    const float* bq = (const float*)d_in[4];
    const float* Wk = (const float*)d_in[5];
    const float* bk = (const float*)d_in[6];
    const float* Wv = (const float*)d_in[7];
    const float* bv = (const float*)d_in[8];
    float* o = (float*)d_out;

    _Float16* ws_h = (_Float16*)d_ws;   // 24 KB used

    hipLaunchKernelGGL(pack_w, dim3(3), dim3(256), 0, stream, Wq, Wk, Wv, ws_h);

    dim3 grid(7, 8, B_DIM);             // (n-tile32, t-chunk, b) = 448 blocks
    dim3 block(512);
    hipLaunchKernelGGL(attn_mfma, grid, block, 0, stream,
                       q, k, v, bq, bk, bv, (const _Float16*)ws_h, o);
}

// Round 2
// 295.215 us; speedup vs baseline: 1.2984x; 1.2984x over previous
//
#include <hip/hip_runtime.h>

typedef _Float16 half8 __attribute__((ext_vector_type(8)));
typedef float floatx4 __attribute__((ext_vector_type(4)));

#define B_DIM 8
#define C_DIM 64
#define T_DIM 128
#define N_DIM 207
#define O_DIM 64
#define CSTR  (T_DIM * N_DIM)

// ---------------------------------------------------------------------------
// Kernel 0: pack Wq|Wk|Wv (fp32 [64 o][64 c]) -> fp16 in d_ws. [arr][o][c].
// ---------------------------------------------------------------------------
__global__ void pack_w(const float* __restrict__ Wq,
                       const float* __restrict__ Wk,
                       const float* __restrict__ Wv,
                       _Float16* __restrict__ ws)
{
    int i = threadIdx.x + blockIdx.x * blockDim.x;
    const int per = O_DIM * C_DIM;          // 4096
    for (int m = i; m < 3 * per; m += blockDim.x * gridDim.x) {
        int arr = m / per, rem = m % per;
        const float* W = (arr == 0) ? Wq : (arr == 1) ? Wk : Wv;
        ws[m] = (_Float16)W[rem];
    }
}

// ---------------------------------------------------------------------------
// Main: t-marching MFMA kernel (round-0 geometry restored).
// Block 256 thr = 4 waves, tile [64 o][16 n], 832 blocks (3.25/CU TLP).
// Changes vs round-0:
//   * barrier = lgkmcnt(0)-only raw s_barrier (NO vmcnt drain) so prefetch
//     loads stay in flight across barriers (T4 / counted-vmcnt pattern)
//   * genuine 2-deep register prefetch (pfA/pfB, statically indexed via
//     2x-unrolled step loop) -> scatter at step r waits only on loads
//     issued at step r-2 (~2 full steps of latency cover)
//   * Q loads/scatter/MFMA skipped on the 6 halo steps
// ---------------------------------------------------------------------------

// LDS-visibility barrier WITHOUT vmcnt drain. Safety: every wave completes
// its own ds ops (lgkmcnt(0)) before signaling; buf is reused only after
// 2 barriers, so no wave can overwrite a buffer another wave still reads.
#define LGKM_BARRIER()                                                       \
    {                                                                        \
        asm volatile("s_waitcnt lgkmcnt(0)" ::: "memory");                   \
        __builtin_amdgcn_sched_barrier(0);                                   \
        __builtin_amdgcn_s_barrier();                                        \
        __builtin_amdgcn_sched_barrier(0);                                   \
    }

// load one t-row of (q?,k,v) into pf[3][4]; 4 channels per thread per array
#define LOADROW(pf, tg1, withQ)                                              \
    {                                                                        \
        const int tcl_ = min(max((tg1), 0), T_DIM - 1);                      \
        if (withQ) {                                                         \
            const float* p_ = qb + (size_t)tcl_ * N_DIM;                     \
            pf[0][0] = p_[(2 * cp2     ) * CSTR];                            \
            pf[0][1] = p_[(2 * cp2 +  1) * CSTR];                            \
            pf[0][2] = p_[(2 * cp2 + 32) * CSTR];                            \
            pf[0][3] = p_[(2 * cp2 + 33) * CSTR];                            \
        }                                                                    \
        {                                                                    \
            const float* p_ = kb + (size_t)tcl_ * N_DIM;                     \
            pf[1][0] = p_[(2 * cp2     ) * CSTR];                            \
            pf[1][1] = p_[(2 * cp2 +  1) * CSTR];                            \
            pf[1][2] = p_[(2 * cp2 + 32) * CSTR];                            \
            pf[1][3] = p_[(2 * cp2 + 33) * CSTR];                            \
        }                                                                    \
        {                                                                    \
            const float* p_ = vb + (size_t)tcl_ * N_DIM;                     \
            pf[2][0] = p_[(2 * cp2     ) * CSTR];                            \
            pf[2][1] = p_[(2 * cp2 +  1) * CSTR];                            \
            pf[2][2] = p_[(2 * cp2 + 32) * CSTR];                            \
            pf[2][3] = p_[(2 * cp2 + 33) * CSTR];                            \
        }                                                                    \
    }

// one t-step: scatter row r (held in pf) to LDS buf, prefetch row r+2 into
// pf, lgkm-barrier, MFMA projections, window shift/insert, emit row r-6.
#define STEP(r, BUF, pf)                                                     \
    {                                                                        \
        const int  r_  = (r);                                                \
        const bool qs_ = (r_ >= 3) && (r_ <= 18);   /* Q useful steps */     \
        {                                                                    \
            auto pk0 = __builtin_amdgcn_cvt_pkrtz(pf[1][0], pf[1][1]);       \
            auto pk1 = __builtin_amdgcn_cvt_pkrtz(pf[1][2], pf[1][3]);       \
            auto pv0 = __builtin_amdgcn_cvt_pkrtz(pf[2][0], pf[2][1]);       \
            auto pv1 = __builtin_amdgcn_cvt_pkrtz(pf[2][2], pf[2][3]);       \
            xw[(BUF) * 1536 + (2 * 64 + wq * 16 + sn) * 4 + jp]              \
                = __builtin_bit_cast(unsigned int, pk0);                     \
            xw[(BUF) * 1536 + (3 * 64 + wq * 16 + sn) * 4 + jp]              \
                = __builtin_bit_cast(unsigned int, pk1);                     \
            xw[(BUF) * 1536 + (4 * 64 + wq * 16 + sn) * 4 + jp]              \
                = __builtin_bit_cast(unsigned int, pv0);                     \
            xw[(BUF) * 1536 + (5 * 64 + wq * 16 + sn) * 4 + jp]              \
                = __builtin_bit_cast(unsigned int, pv1);                     \
            if (qs_) {                                                       \
                auto pq0 = __builtin_amdgcn_cvt_pkrtz(pf[0][0], pf[0][1]);   \
                auto pq1 = __builtin_amdgcn_cvt_pkrtz(pf[0][2], pf[0][3]);   \
                xw[(BUF) * 1536 + (0 * 64 + wq * 16 + sn) * 4 + jp]          \
                    = __builtin_bit_cast(unsigned int, pq0);                 \
                xw[(BUF) * 1536 + (1 * 64 + wq * 16 + sn) * 4 + jp]          \
                    = __builtin_bit_cast(unsigned int, pq1);                 \
            }                                                                \
        }                                                                    \
        if (r_ <= 19) {                             /* rows for step r+2 */  \
            const bool wq_ = (r_ >= 1) && (r_ <= 16);                        \
            LOADROW(pf, t0 - 1 + r_, wq_)                                    \
        }                                                                    \
        LGKM_BARRIER();                                                      \
        floatx4 aq = {0.f, 0.f, 0.f, 0.f};                                   \
        floatx4 ak = {0.f, 0.f, 0.f, 0.f};                                   \
        floatx4 av = {0.f, 0.f, 0.f, 0.f};                                   \
        ak = __builtin_amdgcn_mfma_f32_16x16x32_f16(af[1][0], xsf[BUF][2][lane], ak, 0, 0, 0); \
        ak = __builtin_amdgcn_mfma_f32_16x16x32_f16(af[1][1], xsf[BUF][3][lane], ak, 0, 0, 0); \
        av = __builtin_amdgcn_mfma_f32_16x16x32_f16(af[2][0], xsf[BUF][4][lane], av, 0, 0, 0); \
        av = __builtin_amdgcn_mfma_f32_16x16x32_f16(af[2][1], xsf[BUF][5][lane], av, 0, 0, 0); \
        if (qs_) {                                                           \
            aq = __builtin_amdgcn_mfma_f32_16x16x32_f16(af[0][0], xsf[BUF][0][lane], aq, 0, 0, 0); \
            aq = __builtin_amdgcn_mfma_f32_16x16x32_f16(af[0][1], xsf[BUF][1][lane], aq, 0, 0, 0); \
        }                                                                    \
        const int  tg_   = t0 - 3 + r_;                                      \
        const bool rowv_ = (tg_ >= 0) && (tg_ < T_DIM);                      \
        _Pragma("unroll")                                                    \
        for (int j = 0; j < 4; ++j) {                                        \
            _Pragma("unroll")                                                \
            for (int i = 0; i < 6; ++i) { Kw[j][i] = Kw[j][i + 1]; Vw[j][i] = Vw[j][i + 1]; } \
            _Pragma("unroll")                                                \
            for (int i = 0; i < 3; ++i) Qd4[j][i] = Qd4[j][i + 1];           \
            Kw[j][6]  = rowv_ ? (ak[j] + bk_r[j]) : 0.f;                     \
            Vw[j][6]  = rowv_ ? (av[j] + bv_r[j]) : 0.f;                     \
            Qd4[j][3] = aq[j] + bq_r[j];                                     \
        }                                                                    \
        if (r_ >= 6) {                                                       \
            const int to_ = t0 + r_ - 6;                                     \
            const int n_g = n0 + nq;                                         \
            if (n_g < N_DIM) {                                               \
                _Pragma("unroll")                                            \
                for (int j = 0; j < 4; ++j) {                                \
                    const float qv = Qd4[j][0] * 1.44269504f;                \
                    float s[7];                                              \
                    _Pragma("unroll")                                        \
                    for (int i = 0; i < 7; ++i) s[i] = qv * Kw[j][i];        \
                    float mx = s[0];                                         \
                    _Pragma("unroll")                                        \
                    for (int i = 1; i < 7; ++i) mx = fmaxf(mx, s[i]);        \
                    float den = 0.f, num = 0.f;                              \
                    _Pragma("unroll")                                        \
                    for (int i = 0; i < 7; ++i) {                            \
                        float e = exp2f(s[i] - mx);                          \
                        den += e;                                            \
                        num = fmaf(e, Vw[j][i], num);                        \
                    }                                                        \
                    out[((size_t)(b * O_DIM + o0 + qd * 4 + j) * T_DIM + to_) * N_DIM + n_g] \
                        = num * __builtin_amdgcn_rcpf(den);                  \
                }                                                            \
            }                                                                \
        }                                                                    \
    }

__global__ __launch_bounds__(256, 3)
void attn_mfma(const float* __restrict__ q,
               const float* __restrict__ k,
               const float* __restrict__ v,
               const float* __restrict__ bq,
               const float* __restrict__ bk,
               const float* __restrict__ bv,
               const _Float16* __restrict__ wpk,
               float* __restrict__ out)
{
    // [buf][arr*2+kk][lane] fragment-ordered X staging: 2*6*64*16B = 12288 B
    __shared__ half8 xsf[2][6][64];

    const int tid  = threadIdx.x;
    const int lane = tid & 63;
    const int wv   = tid >> 6;        // wave = o-slice
    const int nq   = lane & 15;       // D col (n), A row (m)
    const int qd   = lane >> 4;       // quad

    const int nb = blockIdx.x;        // 0..12 (16 n each)
    const int tc = blockIdx.y;        // 0..7  (16 t each)
    const int b  = blockIdx.z;        // 0..7

    const int t0 = tc * 16;
    const int o0 = wv * 16;
    const int n0 = nb * 16;

    // ---- staging mapping: thread -> (n=sn, c-pairs cp2 & cp2+16) ----
    const int sn  = tid & 15;
    const int cp2 = tid >> 4;         // 0..15
    const int wq  = cp2 >> 2;         // frag quad of staged elements
    const int jp  = cp2 & 3;          // dword-pair index within frag

    const int n_sc = min(n0 + sn, N_DIM - 1);
    const float* qb = q + (size_t)b * C_DIM * CSTR + n_sc;
    const float* kb = k + (size_t)b * C_DIM * CSTR + n_sc;
    const float* vb = v + (size_t)b * C_DIM * CSTR + n_sc;

    // ---- loop-invariant A-fragments: W[o0+m][k], m=nq, k=qd*8+j+kk*32 ----
    half8 af[3][2];
    #pragma unroll
    for (int arr = 0; arr < 3; ++arr)
        #pragma unroll
        for (int kk = 0; kk < 2; ++kk)
            af[arr][kk] = *(const half8*)(wpk + ((size_t)(arr * 64 + o0 + nq) * 64
                                                 + qd * 8 + kk * 32));

    // ---- bias per lane-reg: D row o_l = qd*4+reg ----
    float bq_r[4], bk_r[4], bv_r[4];
    #pragma unroll
    for (int j = 0; j < 4; ++j) {
        const int og = o0 + qd * 4 + j;
        bq_r[j] = bq[og]; bk_r[j] = bk[og]; bv_r[j] = bv[og];
    }

    // ---- rolling windows ----
    float Kw[4][7], Vw[4][7], Qd4[4][4];
    #pragma unroll
    for (int j = 0; j < 4; ++j) {
        #pragma unroll
        for (int i = 0; i < 7; ++i) { Kw[j][i] = 0.f; Vw[j][i] = 0.f; }
        #pragma unroll
        for (int i = 0; i < 4; ++i) Qd4[j][i] = 0.f;
    }

    unsigned int* xw = (unsigned int*)&xsf[0][0][0];

    // ---- 2-deep prefetch: pfA feeds even steps, pfB odd steps ----
    float pfA[3][4], pfB[3][4];
    #pragma unroll
    for (int a2 = 0; a2 < 3; ++a2)
        #pragma unroll
        for (int j = 0; j < 4; ++j) { pfA[a2][j] = 0.f; pfB[a2][j] = 0.f; }

    LOADROW(pfA, t0 - 3, false)       // row for step 0 (halo: no Q)
    LOADROW(pfB, t0 - 2, false)       // row for step 1 (halo: no Q)

    for (int r2 = 0; r2 < 11; ++r2) {
        STEP(2 * r2,     0, pfA);     // buf/pf statically indexed (rule #20)
        STEP(2 * r2 + 1, 1, pfB);
    }
}

extern "C" void kernel_launch(void* const* d_in, const int* in_sizes, int n_in,
                              void* d_out, int out_size, void* d_ws, size_t ws_size,
                              hipStream_t stream)
{
    const float* q  = (const float*)d_in[0];
    const float* k  = (const float*)d_in[1];
    const float* v  = (const float*)d_in[2];
    const float* Wq = (const float*)d_in[3];
    const float* bq = (const float*)d_in[4];
    const float* Wk = (const float*)d_in[5];
    const float* bk = (const float*)d_in[6];
    const float* Wv = (const float*)d_in[7];
    const float* bv = (const float*)d_in[8];
    float* o = (float*)d_out;

    _Float16* ws_h = (_Float16*)d_ws;   // 24 KB used

    hipLaunchKernelGGL(pack_w, dim3(3), dim3(256), 0, stream, Wq, Wk, Wv, ws_h);

    dim3 grid(13, 8, B_DIM);            // (n-tile, t-chunk, b) = 832 blocks
    dim3 block(256);
    hipLaunchKernelGGL(attn_mfma, grid, block, 0, stream,
                       q, k, v, bq, bk, bv, (const _Float16*)ws_h, o);
}

// Round 3
// 271.814 us; speedup vs baseline: 1.4101x; 1.0861x over previous
//
#include <hip/hip_runtime.h>

typedef _Float16 half8 __attribute__((ext_vector_type(8)));
typedef float floatx4 __attribute__((ext_vector_type(4)));
typedef float f32x4 __attribute__((ext_vector_type(4)));
typedef unsigned int uint4v __attribute__((ext_vector_type(4)));

#define B_DIM 8
#define C_DIM 64
#define T_DIM 128
#define N_DIM 207
#define O_DIM 64
#define CSTR  (T_DIM * N_DIM)

// ---------------------------------------------------------------------------
// Kernel 0: pack Wq|Wk|Wv (fp32 [64 o][64 c]) -> fp16 in d_ws. [arr][o][c].
// ---------------------------------------------------------------------------
__global__ void pack_w(const float* __restrict__ Wq,
                       const float* __restrict__ Wk,
                       const float* __restrict__ Wv,
                       _Float16* __restrict__ ws)
{
    int i = threadIdx.x + blockIdx.x * blockDim.x;
    const int per = O_DIM * C_DIM;          // 4096
    for (int m = i; m < 3 * per; m += blockDim.x * gridDim.x) {
        int arr = m / per, rem = m % per;
        const float* W = (arr == 0) ? Wq : (arr == 1) ? Wk : Wv;
        ws[m] = (_Float16)W[rem];
    }
}

// ---------------------------------------------------------------------------
// Main: t-marching MFMA kernel with global_load_lds staging (m201-style).
// Block 256 thr = 4 waves, tile [64 o][16 n], t-chunk 16, grid 832.
// Staging: f32 direct HBM->LDS via global_load_lds (no VGPR round-trip, so
// the compiler inserts NO vmcnt waits for it); explicit counted
// s_waitcnt vmcnt(4) + raw s_barrier per step -> next row's fetch overlaps
// this row's compute. LDS layout [buf][arr][cb=c/4][n][cw=c&3] f32; each
// wave stages cb in [wv*4, wv*4+4) for all 3 arrays = 12 loads/row.
// Consumer: 12x ds_read_b128 + cvt_pkrtz builds the SAME f16 fragments as
// before; MFMA / rolling windows / softmax epilogue unchanged from round 0.
// ---------------------------------------------------------------------------

#define GLDS(gp_, lp_)                                                       \
    __builtin_amdgcn_global_load_lds(                                        \
        (const __attribute__((address_space(1))) void*)(gp_),                \
        (__attribute__((address_space(3))) void*)(lp_), 4, 0, 0)

// stage one t-row (q,k,v) into buffer P_: 12 global_load_lds per wave
#define STAGE(tg_, P_)                                                       \
    {                                                                        \
        const int tcl_  = min(max((tg_), 0), T_DIM - 1);                     \
        const int toff_ = tcl_ * N_DIM;                                      \
        _Pragma("unroll")                                                    \
        for (int arr_ = 0; arr_ < 3; ++arr_) {                               \
            const float* ab_ = (arr_ == 0) ? qb2 : (arr_ == 1) ? kb2 : vb2;  \
            _Pragma("unroll")                                                \
            for (int i_ = 0; i_ < 4; ++i_) {                                 \
                GLDS(ab_ + toff_ + col_off[i_],                              \
                     &xls[P_][arr_][wv * 4 + i_][0][0]);                     \
            }                                                                \
        }                                                                    \
    }

// build f16 MFMA B-fragment (8 c-values for this lane's column nq) from the
// f32 c-block LDS: c = qd*8 + kk*32 + {0..7}  ->  chunks cb0=qd*2+kk*8, cb0+1
#define MKFRAG(P_, arr_, kk_, dst_)                                          \
    {                                                                        \
        const float* ch_ = &xls[P_][arr_][qd * 2 + (kk_) * 8][nq][0];        \
        f32x4 A_ = *(const f32x4*)(ch_);                                     \
        f32x4 B_ = *(const f32x4*)(ch_ + 64);                                \
        uint4v t_;                                                           \
        t_[0] = __builtin_bit_cast(unsigned int, __builtin_amdgcn_cvt_pkrtz(A_[0], A_[1])); \
        t_[1] = __builtin_bit_cast(unsigned int, __builtin_amdgcn_cvt_pkrtz(A_[2], A_[3])); \
        t_[2] = __builtin_bit_cast(unsigned int, __builtin_amdgcn_cvt_pkrtz(B_[0], B_[1])); \
        t_[3] = __builtin_bit_cast(unsigned int, __builtin_amdgcn_cvt_pkrtz(B_[2], B_[3])); \
        dst_ = __builtin_bit_cast(half8, t_);                                \
    }

__global__ __launch_bounds__(256, 3)
void attn_mfma(const float* __restrict__ q,
               const float* __restrict__ k,
               const float* __restrict__ v,
               const float* __restrict__ bq,
               const float* __restrict__ bk,
               const float* __restrict__ bv,
               const _Float16* __restrict__ wpk,
               float* __restrict__ out)
{
    // f32 staging: [buf][arr][cb][n][cw] = 2*3*16*16*4*4B = 24576 B
    __shared__ __align__(16) float xls[2][3][16][16][4];

    const int tid  = threadIdx.x;
    const int lane = tid & 63;
    const int wv   = tid >> 6;        // wave = o-slice, also staging cb-group
    const int nq   = lane & 15;       // D col (n), A row (m)
    const int qd   = lane >> 4;       // quad

    const int nb = blockIdx.x;        // 0..12 (16 n each)
    const int tc = blockIdx.y;        // 0..7  (16 t each)
    const int b  = blockIdx.z;        // 0..7

    const int t0 = tc * 16;
    const int o0 = wv * 16;
    const int n0 = nb * 16;

    // ---- staging lane mapping: lane -> (n = lane>>2, cw = lane&3) ----
    const int cl   = lane & 3;
    const int nrow = lane >> 2;
    const int n_cl = min(n0 + nrow, N_DIM - 1);
    int col_off[4];
    #pragma unroll
    for (int i = 0; i < 4; ++i)
        col_off[i] = ((wv * 4 + i) * 4 + cl) * CSTR + n_cl;

    const float* qb2 = q + (size_t)b * C_DIM * CSTR;
    const float* kb2 = k + (size_t)b * C_DIM * CSTR;
    const float* vb2 = v + (size_t)b * C_DIM * CSTR;

    // ---- loop-invariant A-fragments: W[o0+m][k], m=nq, k=qd*8+j+kk*32 ----
    half8 af[3][2];
    #pragma unroll
    for (int arr = 0; arr < 3; ++arr)
        #pragma unroll
        for (int kk = 0; kk < 2; ++kk)
            af[arr][kk] = *(const half8*)(wpk + ((size_t)(arr * 64 + o0 + nq) * 64
                                                 + qd * 8 + kk * 32));

    // ---- bias per lane-reg: D row o_l = qd*4+reg ----
    float bq_r[4], bk_r[4], bv_r[4];
    #pragma unroll
    for (int j = 0; j < 4; ++j) {
        const int og = o0 + qd * 4 + j;
        bq_r[j] = bq[og]; bk_r[j] = bk[og]; bv_r[j] = bv[og];
    }

    // ---- rolling windows ----
    float Kw[4][7], Vw[4][7], Qd4[4][4];
    #pragma unroll
    for (int j = 0; j < 4; ++j) {
        #pragma unroll
        for (int i = 0; i < 7; ++i) { Kw[j][i] = 0.f; Vw[j][i] = 0.f; }
        #pragma unroll
        for (int i = 0; i < 4; ++i) Qd4[j][i] = 0.f;
    }

    // ---- prologue: stage row t0-3 into buf 0 (12 loads in flight) ----
    STAGE(t0 - 3, 0);

    for (int r = 0; r < 22; ++r) {
        const int p = r & 1;

        // own row-r loads done (counted: leave last step's 4 stores in
        // flight once emitting); then all-waves barrier -> row r fully
        // staged by everyone, everyone done reading buf[1-p].
        if (r <= 6) { asm volatile("s_waitcnt vmcnt(0)"); }
        else        { asm volatile("s_waitcnt vmcnt(4)"); }
        __builtin_amdgcn_s_barrier();
        __builtin_amdgcn_sched_barrier(0);

        // fire-and-forget: fetch row r+1 under this row's compute
        if (r < 21) STAGE(t0 - 2 + r, 1 - p);

        // ---- fragments + projections via MFMA ----
        half8 fq0, fq1, fk0, fk1, fv0, fv1;
        MKFRAG(p, 1, 0, fk0);  MKFRAG(p, 1, 1, fk1);
        MKFRAG(p, 2, 0, fv0);  MKFRAG(p, 2, 1, fv1);
        MKFRAG(p, 0, 0, fq0);  MKFRAG(p, 0, 1, fq1);

        floatx4 aq = {0.f, 0.f, 0.f, 0.f};
        floatx4 ak = {0.f, 0.f, 0.f, 0.f};
        floatx4 av = {0.f, 0.f, 0.f, 0.f};
        ak = __builtin_amdgcn_mfma_f32_16x16x32_f16(af[1][0], fk0, ak, 0, 0, 0);
        ak = __builtin_amdgcn_mfma_f32_16x16x32_f16(af[1][1], fk1, ak, 0, 0, 0);
        av = __builtin_amdgcn_mfma_f32_16x16x32_f16(af[2][0], fv0, av, 0, 0, 0);
        av = __builtin_amdgcn_mfma_f32_16x16x32_f16(af[2][1], fv1, av, 0, 0, 0);
        aq = __builtin_amdgcn_mfma_f32_16x16x32_f16(af[0][0], fq0, aq, 0, 0, 0);
        aq = __builtin_amdgcn_mfma_f32_16x16x32_f16(af[0][1], fq1, aq, 0, 0, 0);

        const int  tg   = t0 - 3 + r;
        const bool rowv = (tg >= 0) && (tg < T_DIM);

        // ---- shift + insert windows ----
        #pragma unroll
        for (int j = 0; j < 4; ++j) {
            #pragma unroll
            for (int i = 0; i < 6; ++i) { Kw[j][i] = Kw[j][i + 1]; Vw[j][i] = Vw[j][i + 1]; }
            #pragma unroll
            for (int i = 0; i < 3; ++i) Qd4[j][i] = Qd4[j][i + 1];
            Kw[j][6]  = rowv ? (ak[j] + bk_r[j]) : 0.f;  // pad rows exact 0 (post-bias)
            Vw[j][6]  = rowv ? (av[j] + bv_r[j]) : 0.f;
            Qd4[j][3] = aq[j] + bq_r[j];
        }

        // ---- emit output row to = t0 + r - 6 ----
        if (r >= 6) {
            const int to  = t0 + r - 6;
            const int n_g = n0 + nq;
            if (n_g < N_DIM) {
                #pragma unroll
                for (int j = 0; j < 4; ++j) {
                    const float qv = Qd4[j][0] * 1.44269504f;  // log2(e): exp2 domain
                    float s[7];
                    #pragma unroll
                    for (int i = 0; i < 7; ++i) s[i] = qv * Kw[j][i];
                    float mx = s[0];
                    #pragma unroll
                    for (int i = 1; i < 7; ++i) mx = fmaxf(mx, s[i]);
                    float den = 0.f, num = 0.f;
                    #pragma unroll
                    for (int i = 0; i < 7; ++i) {
                        float e = exp2f(s[i] - mx);
                        den += e;
                        num = fmaf(e, Vw[j][i], num);
                    }
                    out[((size_t)(b * O_DIM + o0 + qd * 4 + j) * T_DIM + to) * N_DIM + n_g]
                        = num * __builtin_amdgcn_rcpf(den);
                }
            }
        }
    }
}

extern "C" void kernel_launch(void* const* d_in, const int* in_sizes, int n_in,
                              void* d_out, int out_size, void* d_ws, size_t ws_size,
                              hipStream_t stream)
{
    const float* q  = (const float*)d_in[0];
    const float* k  = (const float*)d_in[1];
    const float* v  = (const float*)d_in[2];
    const float* Wq = (const float*)d_in[3];
    const float* bq = (const float*)d_in[4];
    const float* Wk = (const float*)d_in[5];
    const float* bk = (const float*)d_in[6];
    const float* Wv = (const float*)d_in[7];
    const float* bv = (const float*)d_in[8];
    float* o = (float*)d_out;

    _Float16* ws_h = (_Float16*)d_ws;   // 24 KB used

    hipLaunchKernelGGL(pack_w, dim3(3), dim3(256), 0, stream, Wq, Wk, Wv, ws_h);

    dim3 grid(13, 8, B_DIM);            // (n-tile, t-chunk, b) = 832 blocks
    dim3 block(256);
    hipLaunchKernelGGL(attn_mfma, grid, block, 0, stream,
                       q, k, v, bq, bk, bv, (const _Float16*)ws_h, o);
}

// Round 4
// 250.476 us; speedup vs baseline: 1.5303x; 1.0852x over previous
//
#include <hip/hip_runtime.h>

typedef _Float16 half8 __attribute__((ext_vector_type(8)));
typedef float floatx4 __attribute__((ext_vector_type(4)));
typedef float f32x4 __attribute__((ext_vector_type(4)));
typedef unsigned int uint4v __attribute__((ext_vector_type(4)));

#define B_DIM 8
#define C_DIM 64
#define T_DIM 128
#define N_DIM 207
#define O_DIM 64
#define CSTR  (T_DIM * N_DIM)

// ---------------------------------------------------------------------------
// Kernel 0: pack Wq|Wk|Wv (fp32 [64 o][64 c]) -> fp16 in d_ws. [arr][o][c].
// ---------------------------------------------------------------------------
__global__ void pack_w(const float* __restrict__ Wq,
                       const float* __restrict__ Wk,
                       const float* __restrict__ Wv,
                       _Float16* __restrict__ ws)
{
    int i = threadIdx.x + blockIdx.x * blockDim.x;
    const int per = O_DIM * C_DIM;          // 4096
    for (int m = i; m < 3 * per; m += blockDim.x * gridDim.x) {
        int arr = m / per, rem = m % per;
        const float* W = (arr == 0) ? Wq : (arr == 1) ? Wk : Wv;
        ws[m] = (_Float16)W[rem];
    }
}

// ---------------------------------------------------------------------------
// Main: fully-unrolled t-marching MFMA kernel.
//  * 22 steps unrolled -> rolling K/V/Q windows are compile-time circular
//    buffers (zero register moves), per-step constants everywhere.
//  * global_load_lds staging, 3 LDS buffers, 2-row-ahead prefetch with an
//    exact per-step vmcnt table (stores counted; suffix-set math in notes).
//  * bijective XCD swizzle: 832 blocks = 8 x 104; XCD x gets batch x with
//    nb fastest -> line-straddle (nb-neighbors) + t-halo (tc-neighbors)
//    become L2 hits.
// ---------------------------------------------------------------------------

#define GLDS(gp_, lp_)                                                       \
    __builtin_amdgcn_global_load_lds(                                        \
        (const __attribute__((address_space(1))) void*)(gp_),                \
        (__attribute__((address_space(3))) void*)(lp_), 4, 0, 0)

// stage one t-row (q,k,v) into buffer P_: 12 global_load_lds per wave
#define STAGE(tg_, P_)                                                       \
    {                                                                        \
        const int tcl_  = min(max((tg_), 0), T_DIM - 1);                     \
        const int toff_ = tcl_ * N_DIM;                                      \
        _Pragma("unroll")                                                    \
        for (int arr_ = 0; arr_ < 3; ++arr_) {                               \
            const float* ab_ = (arr_ == 0) ? qb2 : (arr_ == 1) ? kb2 : vb2;  \
            _Pragma("unroll")                                                \
            for (int i_ = 0; i_ < 4; ++i_) {                                 \
                GLDS(ab_ + toff_ + col_off[i_],                              \
                     &xls[P_][arr_][wv * 4 + i_][0][0]);                     \
            }                                                                \
        }                                                                    \
    }

// build f16 MFMA B-fragment (8 c-values for lane column nq) from f32 LDS
#define MKFRAG(P_, arr_, kk_, dst_)                                          \
    {                                                                        \
        const float* ch_ = &xls[P_][arr_][qd * 2 + (kk_) * 8][nq][0];        \
        f32x4 A_ = *(const f32x4*)(ch_);                                     \
        f32x4 B_ = *(const f32x4*)(ch_ + 64);                                \
        uint4v t_;                                                           \
        t_[0] = __builtin_bit_cast(unsigned int, __builtin_amdgcn_cvt_pkrtz(A_[0], A_[1])); \
        t_[1] = __builtin_bit_cast(unsigned int, __builtin_amdgcn_cvt_pkrtz(A_[2], A_[3])); \
        t_[2] = __builtin_bit_cast(unsigned int, __builtin_amdgcn_cvt_pkrtz(B_[0], B_[1])); \
        t_[3] = __builtin_bit_cast(unsigned int, __builtin_amdgcn_cvt_pkrtz(B_[2], B_[3])); \
        dst_ = __builtin_bit_cast(half8, t_);                                \
    }

#define MFMA16(a_, b_, c_) __builtin_amdgcn_mfma_f32_16x16x32_f16(a_, b_, c_, 0, 0, 0)

#define VMWAIT(N_) asm volatile("s_waitcnt vmcnt(" #N_ ")" ::: "memory")

// one t-step, r_ and N_ are LITERAL constants.
// vmcnt keep-suffix at step r: loads row r+1 (12, if r<=20) + stores from
// steps r-1, r-2 (4 each, if those steps >= 6). Rows staged 2 ahead.
#define STEP(r_, N_)                                                         \
    {                                                                        \
        __builtin_amdgcn_sched_barrier(0);                                   \
        VMWAIT(N_);                                                          \
        __builtin_amdgcn_s_barrier();                                        \
        __builtin_amdgcn_sched_barrier(0);                                   \
        if ((r_) <= 19) STAGE(t0 - 1 + (r_), ((r_) + 2) % 3)                 \
        __builtin_amdgcn_sched_barrier(0);                                   \
        half8 fk0, fk1, fv0, fv1;                                            \
        MKFRAG((r_) % 3, 1, 0, fk0)  MKFRAG((r_) % 3, 1, 1, fk1)             \
        MKFRAG((r_) % 3, 2, 0, fv0)  MKFRAG((r_) % 3, 2, 1, fv1)             \
        floatx4 aq = {0.f, 0.f, 0.f, 0.f};                                   \
        floatx4 ak = {0.f, 0.f, 0.f, 0.f};                                   \
        floatx4 av = {0.f, 0.f, 0.f, 0.f};                                   \
        ak = MFMA16(af[1][0], fk0, ak);  ak = MFMA16(af[1][1], fk1, ak);     \
        av = MFMA16(af[2][0], fv0, av);  av = MFMA16(af[2][1], fv1, av);     \
        if ((r_) >= 3 && (r_) <= 18) {                                       \
            half8 fq0, fq1;                                                  \
            MKFRAG((r_) % 3, 0, 0, fq0)  MKFRAG((r_) % 3, 0, 1, fq1)         \
            aq = MFMA16(af[0][0], fq0, aq);  aq = MFMA16(af[0][1], fq1, aq); \
        }                                                                    \
        const int  tg_   = t0 - 3 + (r_);                                    \
        const bool rowv_ = (tg_ >= 0) && (tg_ < T_DIM);                      \
        _Pragma("unroll")                                                    \
        for (int j = 0; j < 4; ++j) {                                        \
            Kw[j][(r_) % 7]  = rowv_ ? (ak[j] + bk_r[j]) : 0.f;              \
            Vw[j][(r_) % 7]  = rowv_ ? (av[j] + bv_r[j]) : 0.f;              \
            Qd4[j][(r_) % 4] = aq[j] + bq_r[j];                              \
        }                                                                    \
        if ((r_) >= 6) {                                                     \
            const int to_ = t0 + (r_) - 6;                                   \
            const int n_g = n0 + nq;                                         \
            if (n_g < N_DIM) {                                               \
                _Pragma("unroll")                                            \
                for (int j = 0; j < 4; ++j) {                                \
                    const float qv = Qd4[j][((r_) + 1) % 4] * 1.44269504f;   \
                    float s[7];                                              \
                    _Pragma("unroll")                                        \
                    for (int i = 0; i < 7; ++i)                              \
                        s[i] = qv * Kw[j][((r_) + 1 + i) % 7];               \
                    float mx = s[0];                                         \
                    _Pragma("unroll")                                        \
                    for (int i = 1; i < 7; ++i) mx = fmaxf(mx, s[i]);        \
                    float den = 0.f, num = 0.f;                              \
                    _Pragma("unroll")                                        \
                    for (int i = 0; i < 7; ++i) {                            \
                        float e = exp2f(s[i] - mx);                          \
                        den += e;                                            \
                        num = fmaf(e, Vw[j][((r_) + 1 + i) % 7], num);       \
                    }                                                        \
                    out[((size_t)(b * O_DIM + o0 + qd * 4 + j) * T_DIM + to_) * N_DIM + n_g] \
                        = num * __builtin_amdgcn_rcpf(den);                  \
                }                                                            \
            }                                                                \
        }                                                                    \
    }

__global__ __launch_bounds__(256, 3)
void attn_mfma(const float* __restrict__ q,
               const float* __restrict__ k,
               const float* __restrict__ v,
               const float* __restrict__ bq,
               const float* __restrict__ bk,
               const float* __restrict__ bv,
               const _Float16* __restrict__ wpk,
               float* __restrict__ out)
{
    // f32 staging: [buf][arr][cb][n][cw] = 3*3*16*16*4*4B = 36864 B
    __shared__ __align__(16) float xls[3][3][16][16][4];

    const int tid  = threadIdx.x;
    const int lane = tid & 63;
    const int wv   = tid >> 6;        // wave = o-slice, also staging cb-group
    const int nq   = lane & 15;       // D col (n), A row (m)
    const int qd   = lane >> 4;       // quad

    // bijective XCD swizzle: 832 blocks = 8 XCDs x 104; XCD x owns batch x,
    // nb fastest within -> straddle/halo L2 sharing.
    const int bid = (int)blockIdx.x + 13 * ((int)blockIdx.y + 8 * (int)blockIdx.z);
    const int swz = (bid & 7) * 104 + (bid >> 3);
    const int nb  = swz % 13;         // 0..12 (16 n each)
    const int tc  = (swz / 13) & 7;   // 0..7  (16 t each)
    const int b   = swz / 104;        // 0..7

    const int t0 = tc * 16;
    const int o0 = wv * 16;
    const int n0 = nb * 16;

    // ---- staging lane mapping: lane -> (n = lane>>2, cw = lane&3) ----
    const int cl   = lane & 3;
    const int nrow = lane >> 2;
    const int n_cl = min(n0 + nrow, N_DIM - 1);
    int col_off[4];
    #pragma unroll
    for (int i = 0; i < 4; ++i)
        col_off[i] = ((wv * 4 + i) * 4 + cl) * CSTR + n_cl;

    const float* qb2 = q + (size_t)b * C_DIM * CSTR;
    const float* kb2 = k + (size_t)b * C_DIM * CSTR;
    const float* vb2 = v + (size_t)b * C_DIM * CSTR;

    // ---- loop-invariant A-fragments: W[o0+m][k], m=nq, k=qd*8+j+kk*32 ----
    half8 af[3][2];
    #pragma unroll
    for (int arr = 0; arr < 3; ++arr)
        #pragma unroll
        for (int kk = 0; kk < 2; ++kk)
            af[arr][kk] = *(const half8*)(wpk + ((size_t)(arr * 64 + o0 + nq) * 64
                                                 + qd * 8 + kk * 32));

    // ---- bias per lane-reg: D row o_l = qd*4+reg ----
    float bq_r[4], bk_r[4], bv_r[4];
    #pragma unroll
    for (int j = 0; j < 4; ++j) {
        const int og = o0 + qd * 4 + j;
        bq_r[j] = bq[og]; bk_r[j] = bk[og]; bv_r[j] = bv[og];
    }

    // ---- circular windows (statically indexed after unroll) ----
    float Kw[4][7], Vw[4][7], Qd4[4][4];
    #pragma unroll
    for (int j = 0; j < 4; ++j) {
        #pragma unroll
        for (int i = 0; i < 7; ++i) { Kw[j][i] = 0.f; Vw[j][i] = 0.f; }
        #pragma unroll
        for (int i = 0; i < 4; ++i) Qd4[j][i] = 0.f;
    }

    // ---- prologue: stage rows 0,1 (2-ahead) ----
    STAGE(t0 - 3, 0)
    STAGE(t0 - 2, 1)

    // ---- 22 fully-unrolled steps; vmcnt table per keep-suffix math ----
    STEP( 0, 12)  STEP( 1, 12)  STEP( 2, 12)  STEP( 3, 12)
    STEP( 4, 12)  STEP( 5, 12)  STEP( 6, 12)  STEP( 7, 16)
    STEP( 8, 20)  STEP( 9, 20)  STEP(10, 20)  STEP(11, 20)
    STEP(12, 20)  STEP(13, 20)  STEP(14, 20)  STEP(15, 20)
    STEP(16, 20)  STEP(17, 20)  STEP(18, 20)  STEP(19, 20)
    STEP(20, 20)  STEP(21,  8)
}

extern "C" void kernel_launch(void* const* d_in, const int* in_sizes, int n_in,
                              void* d_out, int out_size, void* d_ws, size_t ws_size,
                              hipStream_t stream)
{
    const float* q  = (const float*)d_in[0];
    const float* k  = (const float*)d_in[1];
    const float* v  = (const float*)d_in[2];
    const float* Wq = (const float*)d_in[3];
    const float* bq = (const float*)d_in[4];
    const float* Wk = (const float*)d_in[5];
    const float* bk = (const float*)d_in[6];
    const float* Wv = (const float*)d_in[7];
    const float* bv = (const float*)d_in[8];
    float* o = (float*)d_out;

    _Float16* ws_h = (_Float16*)d_ws;   // 24 KB used

    hipLaunchKernelGGL(pack_w, dim3(3), dim3(256), 0, stream, Wq, Wk, Wv, ws_h);

    dim3 grid(13, 8, B_DIM);            // (n-tile, t-chunk, b) = 832 blocks
    dim3 block(256);
    hipLaunchKernelGGL(attn_mfma, grid, block, 0, stream,
                       q, k, v, bq, bk, bv, (const _Float16*)ws_h, o);
}